// Round 5
// baseline (155.343 us; speedup 1.0000x reference)
//
#include <hip/hip_runtime.h>
#include <hip/hip_bf16.h>
#include <cstdint>

// Problem constants (from reference): B=2, M=256, D=256, DE=64
#define BB 2
#define MM 256
#define DD 256
#define DE 64
#define K2 (2*MM)      // 512
#define WM_LD (DD+DE)  // 320, Wm row stride
#define WH_LD (2*DD)   // 512, Wh row stride

// Persistent scratch (fully overwritten every call before being read)
__device__ float g_fz    [MM*DD];      // batch-0 f rows (asp source for k_attn)
__device__ float g_fproj [BB*MM*DD];   // f @ Wm_f.T
__device__ float g_fnf   [BB*MM];      // f . wa_nf
__device__ float g_WzT   [DD*DD];      // WzT[e][d]    = Wz[d][e]
__device__ float g_WmT   [DD*DD];      // WmT[e][d]    = Wm[d][DE+e]
__device__ float g_WmDepT[DE*DD];      // WmDepT[e][d] = Wm[d][e]
__device__ float g_WhT   [2*DD*DD];    // WhT[c][d]    = Wh[d][c], c in [0,512)

// ------------------------------------------------ transposes + output copy
// 1024 blocks. Coalesced row reads, scattered writes (writes don't stall).
__global__ __launch_bounds__(256) void k_tr(const float* __restrict__ Wz,
                                            const float* __restrict__ Wm,
                                            const float* __restrict__ Wh,
                                            const float4* __restrict__ src,
                                            float4* __restrict__ dst, int n4) {
  const int t = threadIdx.x;
  const int blk = blockIdx.x;
  if (blk < 256) {
    const int d = blk;
    g_WzT[t*DD + d] = Wz[(size_t)d*DD + t];
  } else if (blk < 512) {
    const int d = blk - 256;
    g_WmT[t*DD + d] = Wm[(size_t)d*WM_LD + DE + t];
    if (t < DE) g_WmDepT[t*DD + d] = Wm[(size_t)d*WM_LD + t];
  } else {
    const int idx = blk - 512;           // 0..511
    const int d = idx & 255, half = idx >> 8;
    g_WhT[(size_t)(half*DD + t)*DD + d] = Wh[(size_t)d*WH_LD + half*DD + t];
  }
  const int gidx = blk*256 + t;
  if (gidx < n4) dst[gidx] = src[gidx];
}

// ------------------------------------------------ pre (per 2 rows, all 256 d):
// fz = feats[:,1:] @ Wz.T + bz ; fnf = fz . wa_nf ; fproj = fz @ Wm_f.T
__global__ __launch_bounds__(256) void k_pre(const float* __restrict__ feats,
                                             const float* __restrict__ bz,
                                             const float* __restrict__ Wa) {
  const int blk = blockIdx.x;          // 0..255
  const int b   = blk >> 7;
  const int m0  = (blk & 127) * 2;
  const int t   = threadIdx.x;         // = output dim d

  __shared__ float fin[2][DD];
  __shared__ float fzsh[2][DD];

  fin[0][t] = feats[((size_t)b*(MM+1) + m0 + 1)*DD + t];
  fin[1][t] = feats[((size_t)b*(MM+1) + m0 + 2)*DD + t];
  __syncthreads();

  float a0 = 0.f, a1 = 0.f;
  #pragma unroll 8
  for (int e4 = 0; e4 < DD/4; ++e4) {
    const float4 f0 = *(const float4*)&fin[0][e4*4];
    const float4 f1 = *(const float4*)&fin[1][e4*4];
    const float w0 = g_WzT[(e4*4+0)*DD + t];
    const float w1 = g_WzT[(e4*4+1)*DD + t];
    const float w2 = g_WzT[(e4*4+2)*DD + t];
    const float w3 = g_WzT[(e4*4+3)*DD + t];
    a0 += f0.x*w0 + f0.y*w1 + f0.z*w2 + f0.w*w3;
    a1 += f1.x*w0 + f1.y*w1 + f1.z*w2 + f1.w*w3;
  }
  const float bzt = bz[t];
  a0 += bzt; a1 += bzt;
  fzsh[0][t] = a0; fzsh[1][t] = a1;
  if (b == 0) {
    g_fz[(size_t)(m0    )*DD + t] = a0;
    g_fz[(size_t)(m0 + 1)*DD + t] = a1;
  }
  __syncthreads();

  const int wv = t >> 6, lane = t & 63;
  if (wv < 2) {
    float p = 0.f;
    for (int e = lane; e < DD; e += 64) p += fzsh[wv][e] * Wa[DE + e];
    for (int off = 32; off > 0; off >>= 1) p += __shfl_down(p, off, 64);
    if (lane == 0) g_fnf[b*MM + m0 + wv] = p;
  }

  float p0 = 0.f, p1 = 0.f;
  #pragma unroll 8
  for (int e4 = 0; e4 < DD/4; ++e4) {
    const float4 f0 = *(const float4*)&fzsh[0][e4*4];
    const float4 f1 = *(const float4*)&fzsh[1][e4*4];
    const float w0 = g_WmT[(e4*4+0)*DD + t];
    const float w1 = g_WmT[(e4*4+1)*DD + t];
    const float w2 = g_WmT[(e4*4+2)*DD + t];
    const float w3 = g_WmT[(e4*4+3)*DD + t];
    p0 += f0.x*w0 + f0.y*w1 + f0.z*w2 + f0.w*w3;
    p1 += f1.x*w0 + f1.y*w1 + f1.z*w2 + f1.w*w3;
  }
  g_fproj[((size_t)b*MM + m0    )*DD + t] = p0;
  g_fproj[((size_t)b*MM + m0 + 1)*DD + t] = p1;
}

// ------------------------------------------------ attn: one block per updated row
__global__ __launch_bounds__(256) void k_attn(const float* __restrict__ dta,
                                              const int*   __restrict__ adj,
                                              const int*   __restrict__ a_start,
                                              const int*   __restrict__ a_end,
                                              const float* __restrict__ Wa,
                                              float* __restrict__ out) {
  const int b = blockIdx.x >> 4;
  const int r = blockIdx.x & 15;
  const int i = a_start[b] + r;
  if (i >= a_end[b] || i >= MM) return;   // block-uniform
  const int t = threadIdx.x;
  const int lane = t & 63, wv = t >> 6;

  __shared__ int   act[K2];
  __shared__ float sv [K2];
  __shared__ int   wcnt[8];
  __shared__ float wr  [4];     // aspdot partials
  __shared__ float wrm [4];     // max partials
  __shared__ float wrs [4];     // sum partials
  __shared__ float wadep[DE];
  __shared__ float fz0[DD];     // asp row i
  __shared__ float depsh[64*DE];
  __shared__ float fused_sh[DD];

  // issue long-latency adj reads first (col read is a 1KB-stride gather)
  const int mval0 = adj[((size_t)b*MM + i)*MM + t];
  const int mval1 = adj[((size_t)b*MM + t)*MM + i];
  const float myfz = g_fz[(size_t)i*DD + t];
  fz0[t] = myfz;
  if (t < DE) wadep[t] = Wa[t];

  // aspdot: in-register product + wave shuffle reduce (hides under adj gather)
  {
    float p = myfz * Wa[DE + DD + t];
    for (int off = 32; off > 0; off >>= 1) p += __shfl_down(p, off, 64);
    if (lane == 0) wr[wv] = p;
  }

  // single-sync two-phase compaction
  const bool on0 = (mval0 != 0);
  const bool on1 = (mval1 != 0);
  const unsigned long long b0 = __ballot(on0);
  const unsigned long long b1 = __ballot(on1);
  if (lane == 0) { wcnt[wv] = __popcll(b0); wcnt[4+wv] = __popcll(b1); }
  __syncthreads();                                   // S1: wcnt, wr, fz0, wadep
  const float aspdot_i = wr[0] + wr[1] + wr[2] + wr[3];
  const int tot0 = wcnt[0] + wcnt[1] + wcnt[2] + wcnt[3];
  const int na   = tot0 + wcnt[4] + wcnt[5] + wcnt[6] + wcnt[7];
  {
    int off0 = 0, off1 = tot0;
    for (int w2 = 0; w2 < wv; ++w2) { off0 += wcnt[w2]; off1 += wcnt[4+w2]; }
    off0 += __popcll(b0 & ((1ull << lane) - 1ull));
    off1 += __popcll(b1 & ((1ull << lane) - 1ull));
    if (on0) act[off0] = t;
    if (on1) act[off1] = MM + t;
  }
  __syncthreads();                                   // S2: act

  // ---- s for active k (leaky relu)
  for (int j = t; j < na; j += 256) {
    const int k = act[j];
    const float* dv = (k < MM) ? dta + (((size_t)b*MM + i)*MM + k)*DE
                               : dta + (((size_t)b*MM + (k - MM))*MM + i)*DE;
    float s = 0.f;
    const float4* dv4 = (const float4*)dv;
    #pragma unroll
    for (int e4 = 0; e4 < DE/4; ++e4) {
      const float4 v = dv4[e4];
      s += v.x*wadep[4*e4] + v.y*wadep[4*e4+1] + v.z*wadep[4*e4+2] + v.w*wadep[4*e4+3];
    }
    s += g_fnf[b*MM + (k & (MM-1))] + aspdot_i;
    sv[j] = (s > 0.f) ? s : 0.01f * s;
  }
  // ---- softmax max (wave shuffle + cross-wave)
  {
    float part = -3.4e38f;
    for (int j = t; j < na; j += 256) part = fmaxf(part, sv[j]);
    for (int off = 32; off > 0; off >>= 1) part = fmaxf(part, __shfl_down(part, off, 64));
    if (lane == 0) wrm[wv] = part;
  }
  __syncthreads();                                   // S3: sv, wrm
  const float mx = fmaxf(fmaxf(wrm[0], wrm[1]), fmaxf(wrm[2], wrm[3]));
  {
    float psum = 0.f;
    for (int j = t; j < na; j += 256) { float e = expf(sv[j] - mx); sv[j] = e; psum += e; }
    for (int off = 32; off > 0; off >>= 1) psum += __shfl_down(psum, off, 64);
    if (lane == 0) wrs[wv] = psum;
  }
  __syncthreads();                                   // S4: exp'd sv, wrs
  const float inv = 1.f / (wrs[0] + wrs[1] + wrs[2] + wrs[3]);

  // ---- fused[d] = inv * sum_k e_k * relu(dep_k . Wm_dep[d] + fproj[b,k%M,d])
  const int d = t;
  float wm[DE];
  #pragma unroll 8
  for (int e = 0; e < DE; ++e) wm[e] = g_WmDepT[e*DD + d];   // coalesced streams
  float acc = 0.f;
  for (int base = 0; base < na; base += 64) {
    const int cnt = min(64, na - base);
    const int nf4 = cnt * (DE/4);
    for (int q = t; q < nf4; q += 256) {
      const int jl = q >> 4, e4 = q & 15;
      const int k = act[base + jl];
      const float* dv = (k < MM) ? dta + (((size_t)b*MM + i)*MM + k)*DE
                                 : dta + (((size_t)b*MM + (k - MM))*MM + i)*DE;
      ((float4*)(depsh + jl*DE))[e4] = ((const float4*)dv)[e4];
    }
    __syncthreads();
    for (int jl = 0; jl < cnt; ++jl) {
      const float* dp = depsh + jl*DE;
      float dot = 0.f;
      #pragma unroll
      for (int e4 = 0; e4 < DE/4; ++e4) {
        const float4 v = *(const float4*)(dp + 4*e4);
        dot += v.x*wm[4*e4] + v.y*wm[4*e4+1] + v.z*wm[4*e4+2] + v.w*wm[4*e4+3];
      }
      const int k = act[base + jl];
      float msg = dot + g_fproj[((size_t)b*MM + (k & (MM-1)))*DD + d];
      msg = (msg > 0.f) ? msg : 0.f;
      acc += sv[base + jl] * msg;
    }
    __syncthreads();
  }
  fused_sh[d] = acc * inv;
  __syncthreads();                                   // S5: fused

  // ---- out = relu(fused @ Wh[:,:D].T + asp @ Wh[:,D:].T) via WhT streams
  float o = 0.f;
  #pragma unroll 8
  for (int e = 0; e < DD; ++e) o += fused_sh[e] * g_WhT[(size_t)e*DD + d];
  #pragma unroll 8
  for (int e = 0; e < DD; ++e) o += fz0[e] * g_WhT[(size_t)(DD + e)*DD + d];
  out[((size_t)b*(MM+1) + i + 1)*DD + d] = (o > 0.f) ? o : 0.f;
}

extern "C" void kernel_launch(void* const* d_in, const int* in_sizes, int n_in,
                              void* d_out, int out_size, void* d_ws, size_t ws_size,
                              hipStream_t stream) {
  const float* feats   = (const float*)d_in[0];
  const float* dta     = (const float*)d_in[1];
  const int*   adj     = (const int*)  d_in[2];
  const int*   a_start = (const int*)  d_in[3];
  const int*   a_end   = (const int*)  d_in[4];
  const float* Wz      = (const float*)d_in[5];
  const float* bz      = (const float*)d_in[6];
  const float* Wa      = (const float*)d_in[7];
  const float* Wm      = (const float*)d_in[8];
  const float* Wh      = (const float*)d_in[9];
  float* out = (float*)d_out;

  const int n4 = BB*(MM+1)*DD/4;  // 32896 float4
  k_tr  <<<1024, 256, 0, stream>>>(Wz, Wm, Wh, (const float4*)feats, (float4*)out, n4);
  k_pre <<<BB*MM/2, 256, 0, stream>>>(feats, bz, Wa);
  k_attn<<<BB*16, 256, 0, stream>>>(dta, adj, a_start, a_end, Wa, out);
}

// Round 7
// 147.876 us; speedup vs baseline: 1.0505x; 1.0505x over previous
//
#include <hip/hip_runtime.h>
#include <hip/hip_bf16.h>
#include <cstdint>

// Problem constants (from reference): B=2, M=256, D=256, DE=64
#define BB 2
#define MM 256
#define DD 256
#define DE 64
#define K2 (2*MM)      // 512
#define WM_LD (DD+DE)  // 320, Wm row stride
#define WH_LD (2*DD)   // 512, Wh row stride
#define DEP_LD 68      // padded depsh row (floats); 272B keeps 16B alignment

// Persistent scratch (fully overwritten every call before being read)
__device__ float g_fz    [MM*DD];      // batch-0 f rows
__device__ float g_fproj [BB*MM*DD];   // f @ Wm_f.T
__device__ float g_fnf   [BB*MM];      // f . wa_nf
__device__ float g_aspdot[MM];         // asp . wa_asp   (per row i)
__device__ float g_asph  [MM*DD];      // asp @ Wh[:,D:].T (per row i)
__device__ float g_WzT   [DD*DD];      // WzT[e][d]    = Wz[d][e]
__device__ float g_WmT   [DD*DD];      // WmT[e][d]    = Wm[d][DE+e]
__device__ float g_WmDepT[DE*DD];      // WmDepT[e][d] = Wm[d][e]
__device__ float g_WhT   [2*DD*DD];    // WhT[c][d]    = Wh[d][c], c in [0,512)

// ------------------------------------------------ transposes + output copy
__global__ __launch_bounds__(256) void k_tr(const float* __restrict__ Wz,
                                            const float* __restrict__ Wm,
                                            const float* __restrict__ Wh,
                                            const float4* __restrict__ src,
                                            float4* __restrict__ dst, int n4) {
  const int t = threadIdx.x;
  const int blk = blockIdx.x;
  if (blk < 256) {
    const int d = blk;
    g_WzT[t*DD + d] = Wz[(size_t)d*DD + t];
  } else if (blk < 512) {
    const int d = blk - 256;
    g_WmT[t*DD + d] = Wm[(size_t)d*WM_LD + DE + t];
    if (t < DE) g_WmDepT[t*DD + d] = Wm[(size_t)d*WM_LD + t];
  } else {
    const int idx = blk - 512;           // 0..511
    const int d = idx & 255, half = idx >> 8;
    g_WhT[(size_t)(half*DD + t)*DD + d] = Wh[(size_t)d*WH_LD + half*DD + t];
  }
  const int gidx = blk*256 + t;
  if (gidx < n4) dst[gidx] = src[gidx];
}

// ------------------------------------------------ pre (per 2 rows, all 256 d):
// fz ; fnf ; aspdot (b0) ; fproj ; asph (b0)
__global__ __launch_bounds__(256) void k_pre(const float* __restrict__ feats,
                                             const float* __restrict__ bz,
                                             const float* __restrict__ Wa) {
  const int blk = blockIdx.x;          // 0..255
  const int b   = blk >> 7;
  const int m0  = (blk & 127) * 2;
  const int t   = threadIdx.x;         // = output dim d

  __shared__ float fin[2][DD];
  __shared__ float fzsh[2][DD];

  fin[0][t] = feats[((size_t)b*(MM+1) + m0 + 1)*DD + t];
  fin[1][t] = feats[((size_t)b*(MM+1) + m0 + 2)*DD + t];
  __syncthreads();

  float a0 = 0.f, a1 = 0.f;
  #pragma unroll 8
  for (int e4 = 0; e4 < DD/4; ++e4) {
    const float4 f0 = *(const float4*)&fin[0][e4*4];
    const float4 f1 = *(const float4*)&fin[1][e4*4];
    const float w0 = g_WzT[(e4*4+0)*DD + t];
    const float w1 = g_WzT[(e4*4+1)*DD + t];
    const float w2 = g_WzT[(e4*4+2)*DD + t];
    const float w3 = g_WzT[(e4*4+3)*DD + t];
    a0 += f0.x*w0 + f0.y*w1 + f0.z*w2 + f0.w*w3;
    a1 += f1.x*w0 + f1.y*w1 + f1.z*w2 + f1.w*w3;
  }
  const float bzt = bz[t];
  a0 += bzt; a1 += bzt;
  fzsh[0][t] = a0; fzsh[1][t] = a1;
  if (b == 0) {
    g_fz[(size_t)(m0    )*DD + t] = a0;
    g_fz[(size_t)(m0 + 1)*DD + t] = a1;
  }
  __syncthreads();

  const int wv = t >> 6, lane = t & 63;
  if (wv < 2) {            // fnf rows 0,1
    float p = 0.f;
    for (int e = lane; e < DD; e += 64) p += fzsh[wv][e] * Wa[DE + e];
    for (int off = 32; off > 0; off >>= 1) p += __shfl_down(p, off, 64);
    if (lane == 0) g_fnf[b*MM + m0 + wv] = p;
  } else if (b == 0) {     // aspdot rows 0,1 (waves 2,3)
    const int rr = wv - 2;
    float p = 0.f;
    for (int e = lane; e < DD; e += 64) p += fzsh[rr][e] * Wa[DE + DD + e];
    for (int off = 32; off > 0; off >>= 1) p += __shfl_down(p, off, 64);
    if (lane == 0) g_aspdot[m0 + rr] = p;
  }

  float p0 = 0.f, p1 = 0.f;
  #pragma unroll 8
  for (int e4 = 0; e4 < DD/4; ++e4) {
    const float4 f0 = *(const float4*)&fzsh[0][e4*4];
    const float4 f1 = *(const float4*)&fzsh[1][e4*4];
    const float w0 = g_WmT[(e4*4+0)*DD + t];
    const float w1 = g_WmT[(e4*4+1)*DD + t];
    const float w2 = g_WmT[(e4*4+2)*DD + t];
    const float w3 = g_WmT[(e4*4+3)*DD + t];
    p0 += f0.x*w0 + f0.y*w1 + f0.z*w2 + f0.w*w3;
    p1 += f1.x*w0 + f1.y*w1 + f1.z*w2 + f1.w*w3;
  }
  g_fproj[((size_t)b*MM + m0    )*DD + t] = p0;
  g_fproj[((size_t)b*MM + m0 + 1)*DD + t] = p1;

  if (b == 0) {            // asph = fz @ Wh[:, D:].T  via WhT second half
    float q0 = 0.f, q1 = 0.f;
    #pragma unroll 8
    for (int e4 = 0; e4 < DD/4; ++e4) {
      const float4 f0 = *(const float4*)&fzsh[0][e4*4];
      const float4 f1 = *(const float4*)&fzsh[1][e4*4];
      const float w0 = g_WhT[(size_t)(DD + e4*4+0)*DD + t];
      const float w1 = g_WhT[(size_t)(DD + e4*4+1)*DD + t];
      const float w2 = g_WhT[(size_t)(DD + e4*4+2)*DD + t];
      const float w3 = g_WhT[(size_t)(DD + e4*4+3)*DD + t];
      q0 += f0.x*w0 + f0.y*w1 + f0.z*w2 + f0.w*w3;
      q1 += f1.x*w0 + f1.y*w1 + f1.z*w2 + f1.w*w3;
    }
    g_asph[(size_t)(m0    )*DD + t] = q0;
    g_asph[(size_t)(m0 + 1)*DD + t] = q1;
  }
}

// ------------------------------------------------ attn: one block per updated row
__global__ __launch_bounds__(256, 1) void k_attn(const float* __restrict__ dta,
                                                 const int*   __restrict__ adj,
                                                 const int*   __restrict__ a_start,
                                                 const int*   __restrict__ a_end,
                                                 const float* __restrict__ Wa,
                                                 float* __restrict__ out) {
  const int b = blockIdx.x >> 4;
  const int r = blockIdx.x & 15;
  const int i = a_start[b] + r;
  if (i >= a_end[b] || i >= MM) return;   // block-uniform
  const int t = threadIdx.x;
  const int lane = t & 63, wv = t >> 6;
  const int d = t;

  __shared__ int   act[K2];
  __shared__ float sv [K2];
  __shared__ int   wcnt[8];
  __shared__ float wrm [4];
  __shared__ float wrs [4];
  __shared__ float wadep[DE];
  __shared__ float fnfsh[MM];
  __shared__ float depsh[64*DEP_LD];
  __shared__ float fused_sh[DD];

  // ---- hoisted independent long-latency loads
  const int mval0 = adj[((size_t)b*MM + i)*MM + t];          // row (coalesced)
  const int mval1 = adj[((size_t)b*MM + t)*MM + i];          // col (1KB-stride gather)
  float wm[DE];                                              // Wm[:, :DE] row d, via coalesced WmDepT streams
  #pragma unroll
  for (int e = 0; e < DE; ++e) wm[e] = g_WmDepT[e*DD + d];
  fnfsh[t] = g_fnf[b*MM + t];
  if (t < DE) wadep[t] = Wa[t];
  const float aspdot_i = g_aspdot[i];
  const float asph_i   = g_asph[(size_t)i*DD + d];

  // ---- single-sync two-phase compaction
  const bool on0 = (mval0 != 0);
  const bool on1 = (mval1 != 0);
  const unsigned long long b0 = __ballot(on0);
  const unsigned long long b1 = __ballot(on1);
  if (lane == 0) { wcnt[wv] = __popcll(b0); wcnt[4+wv] = __popcll(b1); }
  __syncthreads();                                   // S1: wcnt, wadep, fnfsh
  const int tot0 = wcnt[0] + wcnt[1] + wcnt[2] + wcnt[3];
  const int na   = tot0 + wcnt[4] + wcnt[5] + wcnt[6] + wcnt[7];
  {
    int off0 = 0, off1 = tot0;
    for (int w2 = 0; w2 < wv; ++w2) { off0 += wcnt[w2]; off1 += wcnt[4+w2]; }
    off0 += __popcll(b0 & ((1ull << lane) - 1ull));
    off1 += __popcll(b1 & ((1ull << lane) - 1ull));
    if (on0) act[off0] = t;
    if (on1) act[off1] = MM + t;
  }
  __syncthreads();                                   // S2: act

  // ---- s-phase: 4 threads per active k; also stages chunk-0 dep vectors
  const int jj = t >> 2, sub = t & 3;
  for (int base = 0; base < na; base += 64) {
    const int j = base + jj;
    float p = 0.f; int k = 0;
    if (j < na) {
      k = act[j];
      const float* dv = (k < MM) ? dta + (((size_t)b*MM + i)*MM + k)*DE
                                 : dta + (((size_t)b*MM + (k - MM))*MM + i)*DE;
      const float4* dv4 = (const float4*)dv + sub*4;
      const float4 v0 = dv4[0], v1 = dv4[1], v2 = dv4[2], v3 = dv4[3];
      const float* wa = wadep + sub*16;
      p = v0.x*wa[0]  + v0.y*wa[1]  + v0.z*wa[2]  + v0.w*wa[3]
        + v1.x*wa[4]  + v1.y*wa[5]  + v1.z*wa[6]  + v1.w*wa[7]
        + v2.x*wa[8]  + v2.y*wa[9]  + v2.z*wa[10] + v2.w*wa[11]
        + v3.x*wa[12] + v3.y*wa[13] + v3.z*wa[14] + v3.w*wa[15];
      if (base == 0) {
        float4* ds = (float4*)(depsh + jj*DEP_LD + sub*16);
        ds[0] = v0; ds[1] = v1; ds[2] = v2; ds[3] = v3;
      }
    }
    p += __shfl_xor(p, 1, 64);
    p += __shfl_xor(p, 2, 64);
    if (j < na && sub == 0) {
      const float s = p + fnfsh[k & (MM-1)] + aspdot_i;
      sv[j] = (s > 0.f) ? s : 0.01f * s;
    }
  }
  __syncthreads();                                   // S3: sv, depsh chunk0

  // ---- softmax over active (wave shuffle + cross-wave)
  {
    float part = -3.4e38f;
    for (int j = t; j < na; j += 256) part = fmaxf(part, sv[j]);
    for (int off = 32; off > 0; off >>= 1) part = fmaxf(part, __shfl_down(part, off, 64));
    if (lane == 0) wrm[wv] = part;
  }
  __syncthreads();                                   // S4
  const float mx = fmaxf(fmaxf(wrm[0], wrm[1]), fmaxf(wrm[2], wrm[3]));
  {
    float psum = 0.f;
    for (int j = t; j < na; j += 256) { float e = expf(sv[j] - mx); sv[j] = e; psum += e; }
    for (int off = 32; off > 0; off >>= 1) psum += __shfl_down(psum, off, 64);
    if (lane == 0) wrs[wv] = psum;
  }
  __syncthreads();                                   // S5
  const float inv = 1.f / (wrs[0] + wrs[1] + wrs[2] + wrs[3]);
  for (int j = t; j < na; j += 256) sv[j] *= inv;    // own elements only
  __syncthreads();                                   // S6: normalized sv

  // ---- fused[d] = sum_k w_k * relu(dep_k . Wm_dep[d] + fproj[b,k%M,d])
  float acc = 0.f;
  for (int base = 0; base < na; base += 64) {
    const int cnt = min(64, na - base);
    if (base > 0) {                                  // restage (rare: na>64)
      __syncthreads();
      const int nf4 = cnt * (DE/4);
      for (int q = t; q < nf4; q += 256) {
        const int jl = q >> 4, e4 = q & 15;
        const int k = act[base + jl];
        const float* dv = (k < MM) ? dta + (((size_t)b*MM + i)*MM + k)*DE
                                   : dta + (((size_t)b*MM + (k - MM))*MM + i)*DE;
        *(float4*)(depsh + jl*DEP_LD + e4*4) = ((const float4*)dv)[e4];
      }
      __syncthreads();
    }
    #pragma unroll 2
    for (int jl = 0; jl < cnt; ++jl) {
      const int k = act[base + jl];
      const float* dp = depsh + jl*DEP_LD;
      float dot = 0.f;
      #pragma unroll
      for (int e4 = 0; e4 < DE/4; ++e4) {
        const float4 v = *(const float4*)(dp + 4*e4);
        dot += v.x*wm[4*e4] + v.y*wm[4*e4+1] + v.z*wm[4*e4+2] + v.w*wm[4*e4+3];
      }
      float msg = dot + g_fproj[((size_t)b*MM + (k & (MM-1)))*DD + d];
      msg = (msg > 0.f) ? msg : 0.f;
      acc += sv[base + jl] * msg;
    }
  }
  fused_sh[d] = acc;
  __syncthreads();                                   // S7: fused

  // ---- out = relu(fused @ Wh[:,:D].T + asph_i)  via coalesced WhT streams
  float o = asph_i;
  #pragma unroll 8
  for (int e4 = 0; e4 < DD/4; ++e4) {
    const float f0 = fused_sh[4*e4+0], f1 = fused_sh[4*e4+1];
    const float f2 = fused_sh[4*e4+2], f3 = fused_sh[4*e4+3];
    o += f0 * g_WhT[(size_t)(4*e4+0)*DD + d]
       + f1 * g_WhT[(size_t)(4*e4+1)*DD + d]
       + f2 * g_WhT[(size_t)(4*e4+2)*DD + d]
       + f3 * g_WhT[(size_t)(4*e4+3)*DD + d];
  }
  out[((size_t)b*(MM+1) + i + 1)*DD + d] = (o > 0.f) ? o : 0.f;
}

extern "C" void kernel_launch(void* const* d_in, const int* in_sizes, int n_in,
                              void* d_out, int out_size, void* d_ws, size_t ws_size,
                              hipStream_t stream) {
  const float* feats   = (const float*)d_in[0];
  const float* dta     = (const float*)d_in[1];
  const int*   adj     = (const int*)  d_in[2];
  const int*   a_start = (const int*)  d_in[3];
  const int*   a_end   = (const int*)  d_in[4];
  const float* Wz      = (const float*)d_in[5];
  const float* bz      = (const float*)d_in[6];
  const float* Wa      = (const float*)d_in[7];
  const float* Wm      = (const float*)d_in[8];
  const float* Wh      = (const float*)d_in[9];
  float* out = (float*)d_out;

  const int n4 = BB*(MM+1)*DD/4;  // 32896 float4
  k_tr  <<<1024, 256, 0, stream>>>(Wz, Wm, Wh, (const float4*)feats, (float4*)out, n4);
  k_pre <<<BB*MM/2, 256, 0, stream>>>(feats, bz, Wa);
  k_attn<<<BB*16, 256, 0, stream>>>(dta, adj, a_start, a_end, Wa, out);
}

// Round 8
// 144.132 us; speedup vs baseline: 1.0778x; 1.0260x over previous
//
#include <hip/hip_runtime.h>
#include <hip/hip_bf16.h>
#include <cstdint>

// Problem constants (from reference): B=2, M=256, D=256, DE=64
#define BB 2
#define MM 256
#define DD 256
#define DE 64
#define K2 (2*MM)      // 512
#define WM_LD (DD+DE)  // 320, Wm row stride
#define WH_LD (2*DD)   // 512, Wh row stride
#define DEP_LD 68      // padded depsh row (floats)

// e4-blocked transposed weights: X4[e4*DD + d] = {X[d][4e4+0..3]} (float4)
__device__ float4 g_Wz4   [64*DD];   // Wz   (256x256)
__device__ float4 g_Wm4   [64*DD];   // Wm[:,DE:] (256x256)
__device__ float4 g_WmDep4[16*DD];   // Wm[:,:DE] (256x64)
__device__ float4 g_Wh4lo [64*DD];   // Wh[:,:256]
__device__ float4 g_Wh4hi [64*DD];   // Wh[:,256:]
// Intermediates
__device__ float g_fproj [BB*MM*DD]; // f @ Wm_f.T
__device__ float g_fnf   [BB*MM];    // f . wa_nf
__device__ float g_aspdot[MM];       // asp . wa_asp
__device__ float g_asph  [MM*DD];    // asp @ Wh[:,D:].T

// ------------------------------------------------ LDS-tiled transposes + copy
__global__ __launch_bounds__(256) void k_tr(const float* __restrict__ Wz,
                                            const float* __restrict__ Wm,
                                            const float* __restrict__ Wh,
                                            const float4* __restrict__ src,
                                            float4* __restrict__ dst, int n4) {
  const int t = threadIdx.x, blk = blockIdx.x;
  const int c = t & 63, r0 = t >> 6;
  __shared__ float tile[64][65];

  // feature copy (independent; issue first)
  const int gidx = blk*256 + t;
  if (gidx < n4) dst[gidx] = src[gidx];

  const float* s = nullptr; float4* d4 = nullptr;
  int ld = 0, row0 = 0, col0 = 0, e4base = 0;
  if (blk < 16)      { s = Wz; ld = DD;    row0 = (blk>>2)*64; col0 = (blk&3)*64;      d4 = g_Wz4;    e4base = (blk&3)*16; }
  else if (blk < 32) { int x = blk-16; s = Wm; ld = WM_LD; row0 = (x>>2)*64; col0 = DE + (x&3)*64; d4 = g_Wm4; e4base = (x&3)*16; }
  else if (blk < 36) { int x = blk-32; s = Wm; ld = WM_LD; row0 = x*64;      col0 = 0;             d4 = g_WmDep4; e4base = 0; }
  else if (blk < 68) { int x = blk-36; int rt = x>>3, cg = x&7; s = Wh; ld = WH_LD; row0 = rt*64; col0 = cg*64;
                       d4 = (cg < 4) ? g_Wh4lo : g_Wh4hi; e4base = (cg&3)*16; }
  if (s) {
    #pragma unroll
    for (int rr = r0; rr < 64; rr += 4)
      tile[rr][c] = s[(size_t)(row0 + rr)*ld + col0 + c];
    __syncthreads();
    #pragma unroll
    for (int je = r0; je < 16; je += 4)
      d4[(size_t)(e4base + je)*DD + row0 + c] =
        make_float4(tile[c][4*je+0], tile[c][4*je+1], tile[c][4*je+2], tile[c][4*je+3]);
  }
}

// ------------------------------------------------ pre (2 rows per block):
// fz ; fnf ; aspdot(b0) ; fproj ; asph(b0)
__global__ __launch_bounds__(256) void k_pre(const float* __restrict__ feats,
                                             const float* __restrict__ bz,
                                             const float* __restrict__ Wa) {
  const int blk = blockIdx.x;          // 0..255
  const int b   = blk >> 7;
  const int m0  = (blk & 127) * 2;
  const int t   = threadIdx.x;         // output dim d

  __shared__ float fin[2][DD];
  __shared__ float fzsh[2][DD];

  fin[0][t] = feats[((size_t)b*(MM+1) + m0 + 1)*DD + t];
  fin[1][t] = feats[((size_t)b*(MM+1) + m0 + 2)*DD + t];
  __syncthreads();

  float a0 = 0.f, a1 = 0.f;
  #pragma unroll 8
  for (int e4 = 0; e4 < 64; ++e4) {
    const float4 w  = g_Wz4[(size_t)e4*DD + t];
    const float4 f0 = *(const float4*)&fin[0][e4*4];
    const float4 f1 = *(const float4*)&fin[1][e4*4];
    a0 += f0.x*w.x + f0.y*w.y + f0.z*w.z + f0.w*w.w;
    a1 += f1.x*w.x + f1.y*w.y + f1.z*w.z + f1.w*w.w;
  }
  const float bzt = bz[t];
  a0 += bzt; a1 += bzt;
  fzsh[0][t] = a0; fzsh[1][t] = a1;
  __syncthreads();

  const int wv = t >> 6, lane = t & 63;
  if (wv < 2) {            // fnf rows 0,1
    float p = 0.f;
    for (int e = lane; e < DD; e += 64) p += fzsh[wv][e] * Wa[DE + e];
    for (int off = 32; off > 0; off >>= 1) p += __shfl_down(p, off, 64);
    if (lane == 0) g_fnf[b*MM + m0 + wv] = p;
  } else if (b == 0) {     // aspdot rows 0,1
    const int rr = wv - 2;
    float p = 0.f;
    for (int e = lane; e < DD; e += 64) p += fzsh[rr][e] * Wa[DE + DD + e];
    for (int off = 32; off > 0; off >>= 1) p += __shfl_down(p, off, 64);
    if (lane == 0) g_aspdot[m0 + rr] = p;
  }

  float p0 = 0.f, p1 = 0.f;
  #pragma unroll 8
  for (int e4 = 0; e4 < 64; ++e4) {
    const float4 w  = g_Wm4[(size_t)e4*DD + t];
    const float4 f0 = *(const float4*)&fzsh[0][e4*4];
    const float4 f1 = *(const float4*)&fzsh[1][e4*4];
    p0 += f0.x*w.x + f0.y*w.y + f0.z*w.z + f0.w*w.w;
    p1 += f1.x*w.x + f1.y*w.y + f1.z*w.z + f1.w*w.w;
  }
  g_fproj[((size_t)b*MM + m0    )*DD + t] = p0;
  g_fproj[((size_t)b*MM + m0 + 1)*DD + t] = p1;

  if (b == 0) {            // asph = fz @ Wh[:, D:].T
    float q0 = 0.f, q1 = 0.f;
    #pragma unroll 8
    for (int e4 = 0; e4 < 64; ++e4) {
      const float4 w  = g_Wh4hi[(size_t)e4*DD + t];
      const float4 f0 = *(const float4*)&fzsh[0][e4*4];
      const float4 f1 = *(const float4*)&fzsh[1][e4*4];
      q0 += f0.x*w.x + f0.y*w.y + f0.z*w.z + f0.w*w.w;
      q1 += f1.x*w.x + f1.y*w.y + f1.z*w.z + f1.w*w.w;
    }
    g_asph[(size_t)(m0    )*DD + t] = q0;
    g_asph[(size_t)(m0 + 1)*DD + t] = q1;
  }
}

// ------------------------------------------------ attn: one block per updated row
__global__ __launch_bounds__(256, 1) void k_attn(const float* __restrict__ dta,
                                                 const int*   __restrict__ adj,
                                                 const int*   __restrict__ a_start,
                                                 const int*   __restrict__ a_end,
                                                 const float* __restrict__ Wa,
                                                 float* __restrict__ out) {
  const int b = blockIdx.x >> 4;
  const int r = blockIdx.x & 15;
  const int i = a_start[b] + r;
  if (i >= a_end[b] || i >= MM) return;   // block-uniform
  const int t = threadIdx.x;
  const int lane = t & 63, wv = t >> 6;
  const int d = t;

  __shared__ int   act[K2];
  __shared__ float sv [K2];
  __shared__ int   wcnt[8];
  __shared__ float wrm [4];
  __shared__ float wrs [4];
  __shared__ float wadep[DE];
  __shared__ float fnfsh[MM];
  __shared__ float depsh[64*DEP_LD];
  __shared__ float fproj_sh[64][DD];
  __shared__ float fused_sh[DD];

  // ---- hoisted independent long-latency loads
  const int mval0 = adj[((size_t)b*MM + i)*MM + t];          // row (coalesced)
  const int mval1 = adj[((size_t)b*MM + t)*MM + i];          // col (gather)
  float4 wm4[16];                                            // Wm_dep row d
  #pragma unroll
  for (int e4 = 0; e4 < 16; ++e4) wm4[e4] = g_WmDep4[(size_t)e4*DD + d];
  fnfsh[t] = g_fnf[b*MM + t];
  if (t < DE) wadep[t] = Wa[t];
  const float aspdot_i = g_aspdot[i];
  const float asph_i   = g_asph[(size_t)i*DD + d];

  // ---- single-sync two-phase compaction
  const bool on0 = (mval0 != 0);
  const bool on1 = (mval1 != 0);
  const unsigned long long b0 = __ballot(on0);
  const unsigned long long b1 = __ballot(on1);
  if (lane == 0) { wcnt[wv] = __popcll(b0); wcnt[4+wv] = __popcll(b1); }
  __syncthreads();                                   // S1
  const int tot0 = wcnt[0] + wcnt[1] + wcnt[2] + wcnt[3];
  const int na   = tot0 + wcnt[4] + wcnt[5] + wcnt[6] + wcnt[7];
  {
    int off0 = 0, off1 = tot0;
    for (int w2 = 0; w2 < wv; ++w2) { off0 += wcnt[w2]; off1 += wcnt[4+w2]; }
    off0 += __popcll(b0 & ((1ull << lane) - 1ull));
    off1 += __popcll(b1 & ((1ull << lane) - 1ull));
    if (on0) act[off0] = t;
    if (on1) act[off1] = MM + t;
  }
  __syncthreads();                                   // S2: act

  // ---- s-phase: 4 threads per active k; stages chunk-0 dep vectors
  const int jj = t >> 2, sub = t & 3;
  for (int base = 0; base < na; base += 64) {
    const int j = base + jj;
    float p = 0.f; int k = 0;
    if (j < na) {
      k = act[j];
      const float* dv = (k < MM) ? dta + (((size_t)b*MM + i)*MM + k)*DE
                                 : dta + (((size_t)b*MM + (k - MM))*MM + i)*DE;
      const float4* dv4 = (const float4*)dv + sub*4;
      const float4 v0 = dv4[0], v1 = dv4[1], v2 = dv4[2], v3 = dv4[3];
      const float* wa = wadep + sub*16;
      p = v0.x*wa[0]  + v0.y*wa[1]  + v0.z*wa[2]  + v0.w*wa[3]
        + v1.x*wa[4]  + v1.y*wa[5]  + v1.z*wa[6]  + v1.w*wa[7]
        + v2.x*wa[8]  + v2.y*wa[9]  + v2.z*wa[10] + v2.w*wa[11]
        + v3.x*wa[12] + v3.y*wa[13] + v3.z*wa[14] + v3.w*wa[15];
      if (base == 0) {
        float4* ds = (float4*)(depsh + jj*DEP_LD + sub*16);
        ds[0] = v0; ds[1] = v1; ds[2] = v2; ds[3] = v3;
      }
    }
    p += __shfl_xor(p, 1, 64);
    p += __shfl_xor(p, 2, 64);
    if (j < na && sub == 0) {
      const float s = p + fnfsh[k & (MM-1)] + aspdot_i;
      sv[j] = (s > 0.f) ? s : 0.01f * s;
    }
  }

  // ---- prefetch chunk-0 fproj rows into registers (overlaps softmax)
  const int cnt0 = (na < 64) ? na : 64;
  const int nq0  = cnt0 * 64;                        // float4s to stage
  float4 stash[16];
  #pragma unroll
  for (int rr = 0; rr < 16; ++rr) {
    const int q = t + rr*256;
    if (q < nq0) {
      const int jl = q >> 6, c4 = q & 63;
      const int k = act[jl];
      stash[rr] = *((const float4*)(g_fproj + ((size_t)b*MM + (k & (MM-1)))*DD) + c4);
    }
  }
  __syncthreads();                                   // S3: sv, depsh chunk0

  // ---- softmax over active
  {
    float part = -3.4e38f;
    for (int j = t; j < na; j += 256) part = fmaxf(part, sv[j]);
    for (int off = 32; off > 0; off >>= 1) part = fmaxf(part, __shfl_down(part, off, 64));
    if (lane == 0) wrm[wv] = part;
  }
  __syncthreads();                                   // S4
  const float mx = fmaxf(fmaxf(wrm[0], wrm[1]), fmaxf(wrm[2], wrm[3]));
  {
    float psum = 0.f;
    for (int j = t; j < na; j += 256) { float e = expf(sv[j] - mx); sv[j] = e; psum += e; }
    for (int off = 32; off > 0; off >>= 1) psum += __shfl_down(psum, off, 64);
    if (lane == 0) wrs[wv] = psum;
  }
  __syncthreads();                                   // S5
  const float inv = 1.f / (wrs[0] + wrs[1] + wrs[2] + wrs[3]);
  for (int j = t; j < na; j += 256) sv[j] *= inv;
  // dump fproj stash to LDS
  #pragma unroll
  for (int rr = 0; rr < 16; ++rr) {
    const int q = t + rr*256;
    if (q < nq0) { const int jl = q >> 6, c4 = q & 63; *(float4*)&fproj_sh[jl][c4*4] = stash[rr]; }
  }
  __syncthreads();                                   // S6: sv norm, fproj chunk0

  // ---- fused[d] = sum_k w_k * relu(dep_k . Wm_dep[d] + fproj[k])   (LDS-only)
  float acc = 0.f;
  for (int base = 0; base < na; base += 64) {
    const int cnt = min(64, na - base);
    if (base > 0) {                                  // rare: na > 64 — restage
      __syncthreads();
      for (int q = t; q < cnt*64; q += 256) {
        const int jl = q >> 6, c4 = q & 63;
        const int k = act[base + jl];
        *(float4*)&fproj_sh[jl][c4*4] =
          *((const float4*)(g_fproj + ((size_t)b*MM + (k & (MM-1)))*DD) + c4);
      }
      for (int q = t; q < cnt*16; q += 256) {
        const int jl = q >> 4, e4 = q & 15;
        const int k = act[base + jl];
        const float* dv = (k < MM) ? dta + (((size_t)b*MM + i)*MM + k)*DE
                                   : dta + (((size_t)b*MM + (k - MM))*MM + i)*DE;
        *(float4*)(depsh + jl*DEP_LD + e4*4) = ((const float4*)dv)[e4];
      }
      __syncthreads();
    }
    #pragma unroll 2
    for (int jl = 0; jl < cnt; ++jl) {
      const float4* dp = (const float4*)(depsh + jl*DEP_LD);
      float dot = 0.f;
      #pragma unroll
      for (int e4 = 0; e4 < 16; ++e4) {
        const float4 v = dp[e4];
        const float4 w = wm4[e4];
        dot += v.x*w.x + v.y*w.y + v.z*w.z + v.w*w.w;
      }
      float msg = dot + fproj_sh[jl][d];
      msg = (msg > 0.f) ? msg : 0.f;
      acc += sv[base + jl] * msg;
    }
  }
  fused_sh[d] = acc;
  __syncthreads();                                   // S7

  // ---- out = relu(fused @ Wh[:,:D].T + asph_i)  via float4 Wh4lo streams
  float o = asph_i;
  #pragma unroll 8
  for (int e4 = 0; e4 < 64; ++e4) {
    const float4 w = g_Wh4lo[(size_t)e4*DD + d];
    const float4 f = *(const float4*)&fused_sh[e4*4];
    o += f.x*w.x + f.y*w.y + f.z*w.z + f.w*w.w;
  }
  out[((size_t)b*(MM+1) + i + 1)*DD + d] = (o > 0.f) ? o : 0.f;
}

extern "C" void kernel_launch(void* const* d_in, const int* in_sizes, int n_in,
                              void* d_out, int out_size, void* d_ws, size_t ws_size,
                              hipStream_t stream) {
  const float* feats   = (const float*)d_in[0];
  const float* dta     = (const float*)d_in[1];
  const int*   adj     = (const int*)  d_in[2];
  const int*   a_start = (const int*)  d_in[3];
  const int*   a_end   = (const int*)  d_in[4];
  const float* Wz      = (const float*)d_in[5];
  const float* bz      = (const float*)d_in[6];
  const float* Wa      = (const float*)d_in[7];
  const float* Wm      = (const float*)d_in[8];
  const float* Wh      = (const float*)d_in[9];
  float* out = (float*)d_out;

  const int n4 = BB*(MM+1)*DD/4;  // 32896 float4
  k_tr  <<<132, 256, 0, stream>>>(Wz, Wm, Wh, (const float4*)feats, (float4*)out, n4);
  k_pre <<<BB*MM/2, 256, 0, stream>>>(feats, bz, Wa);
  k_attn<<<BB*16, 256, 0, stream>>>(dta, adj, a_start, a_end, Wa, out);
}